// Round 5
// baseline (77.838 us; speedup 1.0000x reference)
//
#include <hip/hip_runtime.h>
#include <stdint.h>

// out[b,e] = (x_b - c_e)^T Sigma_e^{-1} (x_b - c_e);  E=32, B=8192, D=256, f32.
//  k_inv : (a) converts a 16KB slice of X to bf16 (folded former k_x);
//          (b) Neumann inverse Inv = I - M + M^2 - M^3 (M = Sigma - I, ||M||~0.045),
//          K-blocked output layout [e][k>>3][n][k&7] (32-k chunk = contiguous)
//  k_v   : v2[e] = 2*Inv_e c_e, s[e] = c^T Inv c
//  k_main: grid(8 eg, 64 bt) = 512 blocks = 2/CU (80KB LDS), 4 waves.
//          X tile 128b x 256k in LDS, XOR-swizzled (byte ^= (row&31)<<4) via
//          pre-swizzled gl2lds SOURCE; Inv streamed in 16-k chunks (8KB contiguous)
//          into 2x8KB dbuf; 32x32x16 MFMA; cross-block overlap hides barriers.
// R4: 2 blocks/CU was the lever (R3 was 1 block/CU lockstep at 3.6x its pipe floor).

#define NE 32
#define NB 8192
#define DD 256

typedef __bf16 bf16_t;
typedef bf16_t bf16x8 __attribute__((ext_vector_type(8)));
typedef bf16_t bf16x4 __attribute__((ext_vector_type(4)));
typedef float  f32x4  __attribute__((ext_vector_type(4)));
typedef float  f32x16 __attribute__((ext_vector_type(16)));

#define LDX 264  // k_inv M tile row stride (528B: 2-way max)
#define LDT 264  // k_inv T2t row stride

static __device__ __forceinline__ void gl2lds16(const void* g, void* l) {
  __builtin_amdgcn_global_load_lds((__attribute__((address_space(1))) void*)(g),
                                   (__attribute__((address_space(3))) void*)(l),
                                   16, 0, 0);
}

// ---------------- k_inv : X-convert slice + fused Neumann inverse ----------------
// grid (8 col-chunks, NE e), 512 threads = 8 waves.
__global__ __launch_bounds__(512, 2) void k_inv(const float* __restrict__ Sg,
                                                const float* __restrict__ x,
                                                bf16_t* __restrict__ Xbf,
                                                bf16_t* __restrict__ Invbf) {
  int ct = blockIdx.x;
  int e  = blockIdx.y;
  int tid = threadIdx.x, w = tid >> 6, l = tid & 63;
  __shared__ bf16_t Ml[256 * LDX];   // 132KB padded M
  __shared__ bf16_t T2t[32 * LDT];   // 16.5KB  T2t[c][n] = T2[n][cg]
  const float* Se = Sg + (size_t)e * 65536;

  // ---- folded k_x: convert 16 elems of x per thread (block slice = 8192) ----
  {
    int off = (blockIdx.x + 8 * blockIdx.y) * 8192 + tid * 16;
    f32x4 a0 = *(const f32x4*)(x + off);
    f32x4 a1 = *(const f32x4*)(x + off + 4);
    f32x4 a2 = *(const f32x4*)(x + off + 8);
    f32x4 a3 = *(const f32x4*)(x + off + 12);
    bf16x8 o0, o1;
#pragma unroll
    for (int j = 0; j < 4; ++j) {
      o0[j] = (bf16_t)a0[j]; o0[4 + j] = (bf16_t)a1[j];
      o1[j] = (bf16_t)a2[j]; o1[4 + j] = (bf16_t)a3[j];
    }
    *(bf16x8*)(Xbf + off) = o0;
    *(bf16x8*)(Xbf + off + 8) = o1;
  }

  // stage M = Sigma - I (f32->bf16), padded rows
#pragma unroll
  for (int i = 0; i < 16; ++i) {
    int s = i * 512 + tid;
    int row = s >> 5, c8 = (s & 31) * 8;
    f32x4 a = *(const f32x4*)(Se + row * 256 + c8);
    f32x4 b = *(const f32x4*)(Se + row * 256 + c8 + 4);
    float v[8] = {a[0], a[1], a[2], a[3], b[0], b[1], b[2], b[3]};
    int dj = row - c8;
    if (dj >= 0 && dj < 8) v[dj] -= 1.0f;
    bf16x8 o;
#pragma unroll
    for (int j = 0; j < 8; ++j) o[j] = (bf16_t)v[j];
    *(bf16x8*)&Ml[row * LDX + c8] = o;
  }
  __syncthreads();

  int rA = w * 32 + (l & 15);
  int q8 = (l >> 4) * 8;
  int cg0 = ct * 32;

  // GEMM1: V = M*M   (B-frag via symmetry: M[k][cg] = M[cg][k])
  f32x4 acc1[2][2];
#pragma unroll
  for (int i = 0; i < 2; ++i)
#pragma unroll
    for (int j = 0; j < 2; ++j) acc1[i][j] = (f32x4){0.f, 0.f, 0.f, 0.f};
#pragma unroll
  for (int kk = 0; kk < 256; kk += 32) {
    bf16x8 a0 = *(const bf16x8*)&Ml[rA * LDX + kk + q8];
    bf16x8 a1 = *(const bf16x8*)&Ml[(rA + 16) * LDX + kk + q8];
    bf16x8 b0 = *(const bf16x8*)&Ml[(cg0 + (l & 15)) * LDX + kk + q8];
    bf16x8 b1 = *(const bf16x8*)&Ml[(cg0 + 16 + (l & 15)) * LDX + kk + q8];
    acc1[0][0] = __builtin_amdgcn_mfma_f32_16x16x32_bf16(a0, b0, acc1[0][0], 0, 0, 0);
    acc1[0][1] = __builtin_amdgcn_mfma_f32_16x16x32_bf16(a0, b1, acc1[0][1], 0, 0, 0);
    acc1[1][0] = __builtin_amdgcn_mfma_f32_16x16x32_bf16(a1, b0, acc1[1][0], 0, 0, 0);
    acc1[1][1] = __builtin_amdgcn_mfma_f32_16x16x32_bf16(a1, b1, acc1[1][1], 0, 0, 0);
  }
  // T2t[c][n] = delta - M[n][cg] + V[n][cg]
#pragma unroll
  for (int nf = 0; nf < 2; ++nf) {
    int n0 = w * 32 + nf * 16 + (l >> 4) * 4;
#pragma unroll
    for (int cf = 0; cf < 2; ++cf) {
      int cl = cf * 16 + (l & 15), cg = cg0 + cl;
      bf16x4 mr = *(const bf16x4*)&Ml[cg * LDX + n0];
      f32x4 vv = acc1[nf][cf];
      bf16x4 o;
#pragma unroll
      for (int q = 0; q < 4; ++q) {
        float t2 = (((n0 + q) == cg) ? 1.0f : 0.0f) - (float)mr[q] + vv[q];
        o[q] = (bf16_t)t2;
      }
      *(bf16x4*)&T2t[cl * LDT + n0] = o;
    }
  }
  __syncthreads();

  // GEMM2: acc2 = M * T2
  f32x4 acc2[2][2];
#pragma unroll
  for (int i = 0; i < 2; ++i)
#pragma unroll
    for (int j = 0; j < 2; ++j) acc2[i][j] = (f32x4){0.f, 0.f, 0.f, 0.f};
#pragma unroll
  for (int kk = 0; kk < 256; kk += 32) {
    bf16x8 a0 = *(const bf16x8*)&Ml[rA * LDX + kk + q8];
    bf16x8 a1 = *(const bf16x8*)&Ml[(rA + 16) * LDX + kk + q8];
    bf16x8 b0 = *(const bf16x8*)&T2t[(l & 15) * LDT + kk + q8];
    bf16x8 b1 = *(const bf16x8*)&T2t[(16 + (l & 15)) * LDT + kk + q8];
    acc2[0][0] = __builtin_amdgcn_mfma_f32_16x16x32_bf16(a0, b0, acc2[0][0], 0, 0, 0);
    acc2[0][1] = __builtin_amdgcn_mfma_f32_16x16x32_bf16(a0, b1, acc2[0][1], 0, 0, 0);
    acc2[1][0] = __builtin_amdgcn_mfma_f32_16x16x32_bf16(a1, b0, acc2[1][0], 0, 0, 0);
    acc2[1][1] = __builtin_amdgcn_mfma_f32_16x16x32_bf16(a1, b1, acc2[1][1], 0, 0, 0);
  }
  // Inv[n][cg] = delta - acc2, K-blocked: elem(n,c) at (c>>3)*2048 + n*8 + (c&7)
  bf16_t* Ce = Invbf + (size_t)e * 65536;
#pragma unroll
  for (int nf = 0; nf < 2; ++nf) {
    int n0 = w * 32 + nf * 16 + (l >> 4) * 4;
#pragma unroll
    for (int cf = 0; cf < 2; ++cf) {
      int cg = cg0 + cf * 16 + (l & 15);
#pragma unroll
      for (int q = 0; q < 4; ++q) {
        float vv = (((n0 + q) == cg) ? 1.0f : 0.0f) - acc2[nf][cf][q];
        Ce[(cg >> 3) * 2048 + (n0 + q) * 8 + (cg & 7)] = (bf16_t)vv;
      }
    }
  }
}

// ---------------- k_v : v2 = 2*Inv*c, s = c^T Inv c ----------------
__global__ __launch_bounds__(256) void k_v(const bf16_t* __restrict__ Invbf,
                                           const float* __restrict__ Cent,
                                           float* __restrict__ v2,
                                           float* __restrict__ s_out) {
  int e = blockIdx.x, d = threadIdx.x;
  __shared__ float cl[256];
  __shared__ float ps[256];
  cl[d] = Cent[e * 256 + d];
  __syncthreads();
  const bf16_t* Ie = Invbf + (size_t)e * 65536 + d * 8;  // row d, K-blocked layout
  float acc = 0.f;
#pragma unroll
  for (int ksl = 0; ksl < 32; ++ksl) {
    bf16x8 r = *(const bf16x8*)(Ie + ksl * 2048);
#pragma unroll
    for (int j = 0; j < 8; ++j) acc += (float)r[j] * cl[ksl * 8 + j];
  }
  v2[e * 256 + d] = 2.0f * acc;
  ps[d] = cl[d] * acc;
  __syncthreads();
  for (int off = 128; off > 0; off >>= 1) {
    if (d < off) ps[d] += ps[d + off];
    __syncthreads();
  }
  if (d == 0) s_out[e] = ps[0];
}

// ---------------- k_main ----------------
// grid (8 eg, 64 bt): blockIdx.x = eg -> XCD = eg (round-robin by linear id).
// 256 thr = 4 waves (2 wn x 2 wb); e-loop of 4 folded into T = 0..63 (16 chunks/e).
__global__ __launch_bounds__(256, 2) void k_main(const bf16_t* __restrict__ Xbf,
                                                 const bf16_t* __restrict__ Invbf,
                                                 const float* __restrict__ v2g,
                                                 const float* __restrict__ sg,
                                                 float* __restrict__ out) {
  int eg = blockIdx.x;
  int bt = blockIdx.y;
  int tid = threadIdx.x, w = tid >> 6, l = tid & 63;
  __shared__ bf16_t Xl[128 * 256];  // 64KB, swizzled: byte ^= ((row&31)<<4)
  __shared__ bf16_t Invl[2][4096];  // 2x8KB chunk: [2 ksl][256 n][8 k]

  const bf16_t* Xg = Xbf + (size_t)bt * 128 * 256;
  char* Xb = (char*)Xl;

  // ---- one-time X stage via gl2lds, pre-swizzled SOURCE (linear LDS dest) ----
#pragma unroll
  for (int j = 0; j < 16; ++j) {
    int base = (w * 16 + j) * 1024;             // LDS byte offset (wave-uniform)
    int row = (base >> 9) + (l >> 5);           // 2 rows per inst
    int inner = (l & 31) * 16;
    const char* src = (const char*)Xg + row * 512 + (inner ^ ((row & 31) << 4));
    gl2lds16(src, Xb + base);                   // HW adds lane*16 to dest
  }
  // prologue: stage chunk 0 of e0
  {
    const bf16_t* src = Invbf + (size_t)(eg * 4) * 65536;
    bf16_t* dst = (bf16_t*)Invl[0];
    gl2lds16(src + w * 1024 + l * 8,       dst + w * 1024);
    gl2lds16(src + w * 1024 + 512 + l * 8, dst + w * 1024 + 512);
  }
  __syncthreads();

  int wn = w >> 1, wb = w & 1;
  int lrow = l & 31, lhalf = l >> 5;
  int nbase = wn * 128;
  int bbase = wb * 64;

  f32x16 acc[4][2];
#pragma unroll
  for (int nf = 0; nf < 4; ++nf)
#pragma unroll
    for (int cf = 0; cf < 2; ++cf)
#pragma unroll
      for (int q = 0; q < 16; ++q) acc[nf][cf][q] = 0.f;

  for (int T = 0; T < 64; ++T) {
    int c = T & 15, buf = T & 1;
    if (T < 63) {  // prefetch chunk T+1 (8KB contiguous) into other buffer
      int Tn = T + 1;
      const bf16_t* src = Invbf + (size_t)(eg * 4 + (Tn >> 4)) * 65536 + (Tn & 15) * 4096;
      bf16_t* dst = (bf16_t*)Invl[Tn & 1];
      gl2lds16(src + w * 1024 + l * 8,       dst + w * 1024);
      gl2lds16(src + w * 1024 + 512 + l * 8, dst + w * 1024 + 512);
    }
    const bf16_t* Ib = (const bf16_t*)Invl[buf];
    bf16x8 af[4], bfr[2];
#pragma unroll
    for (int nf = 0; nf < 4; ++nf)
      af[nf] = *(const bf16x8*)(Ib + lhalf * 2048 + (nbase + nf * 32 + lrow) * 8);
#pragma unroll
    for (int cf = 0; cf < 2; ++cf) {
      int b = bbase + cf * 32 + lrow;
      int byte = (b * 512 + c * 32 + lhalf * 16) ^ ((b & 31) << 4);
      bfr[cf] = *(const bf16x8*)(Xb + byte);
    }
#pragma unroll
    for (int nf = 0; nf < 4; ++nf)
#pragma unroll
      for (int cf = 0; cf < 2; ++cf)
        acc[nf][cf] = __builtin_amdgcn_mfma_f32_32x32x16_bf16(af[nf], bfr[cf], acc[nf][cf], 0, 0, 0);

    if (c == 15) {  // e-epilogue
      int e = eg * 4 + (T >> 4);
      float bsum[2] = {0.f, 0.f};
#pragma unroll
      for (int nf = 0; nf < 4; ++nf)
#pragma unroll
        for (int g = 0; g < 4; ++g) {
          int n0 = nbase + nf * 32 + 8 * g + 4 * lhalf;
          f32x4 vv = *(const f32x4*)(v2g + e * 256 + n0);
#pragma unroll
          for (int cf = 0; cf < 2; ++cf) {
            int b = bbase + cf * 32 + lrow;
            int byte = (b * 512 + n0 * 2) ^ ((b & 31) << 4);
            bf16x4 xr = *(const bf16x4*)(Xb + byte);
#pragma unroll
            for (int q = 0; q < 4; ++q)
              bsum[cf] += (float)xr[q] * (acc[nf][cf][g * 4 + q] - vv[q]);
          }
        }
      __syncthreads();  // all reads of Invl[buf] done -> reuse as reduction scratch
      float* red = (float*)Invl[buf];  // [2][128] f32
#pragma unroll
      for (int cf = 0; cf < 2; ++cf) {
        float r = bsum[cf];
        r += __shfl_xor(r, 32);  // sum over lhalf
        if (lhalf == 0) red[wn * 128 + bbase + cf * 32 + lrow] = r;
      }
      __syncthreads();
      if (tid < 128) {
        float res = sg[e] + red[tid] + red[128 + tid];
        out[(size_t)(bt * 128 + tid) * 32 + e] = res;
      }
#pragma unroll
      for (int nf = 0; nf < 4; ++nf)
#pragma unroll
        for (int cf = 0; cf < 2; ++cf)
#pragma unroll
          for (int q = 0; q < 16; ++q) acc[nf][cf][q] = 0.f;
    }
    __syncthreads();  // chunk T+1 staged; red safe before next prefetch issue
  }
}

extern "C" void kernel_launch(void* const* d_in, const int* in_sizes, int n_in,
                              void* d_out, int out_size, void* d_ws, size_t ws_size,
                              hipStream_t stream) {
  const float* x    = (const float*)d_in[0];
  const float* cent = (const float*)d_in[1];
  const float* sig  = (const float*)d_in[2];
  float* out = (float*)d_out;

  char* ws = (char*)d_ws;
  bf16_t* Xbf   = (bf16_t*)(ws);                 // 4MB
  bf16_t* Invbf = (bf16_t*)(ws + (4ull << 20));  // 4MB (K-blocked layout)
  float*  v2    = (float*)(ws + (8ull << 20));   // 32KB
  float*  sArr  = (float*)(ws + (8ull << 20) + 32768);

  k_inv <<<dim3(8, NE),  dim3(512), 0, stream>>>(sig, x, Xbf, Invbf);
  k_v   <<<dim3(NE),     dim3(256), 0, stream>>>(Invbf, cent, v2, sArr);
  k_main<<<dim3(8, 64),  dim3(256), 0, stream>>>(Xbf, Invbf, v2, sArr, out);
}